// Round 1
// baseline (525.515 us; speedup 1.0000x reference)
//
#include <hip/hip_runtime.h>

#define TT 512
#define BB 64
#define HH 5
#define NPOS 1023  // 2T-1

typedef __bf16 bf16x8 __attribute__((ext_vector_type(8)));
typedef __bf16 bf16x4 __attribute__((ext_vector_type(4)));
typedef float floatx4 __attribute__((ext_vector_type(4)));

// ---------- prep: W transpose->bf16 (blocks 0..383) + pe projection (blocks 384..511, f32 out) ----------
__global__ void prep_kernel(const float* __restrict__ Wlm, const float* __restrict__ Wam,
                            const float* __restrict__ pos_emb, const float* __restrict__ Wpos,
                            __bf16* __restrict__ WlmT, __bf16* __restrict__ WamT,
                            float* __restrict__ peF) {
  int bx = blockIdx.x;
  if (bx < 384) {
    int idx = bx * 256 + threadIdx.x;
    if (idx < 192 * 512) {
      int n = idx >> 9, k = idx & 511;
      float v = (n < 180) ? Wlm[k * 180 + n] : 0.f;
      WlmT[idx] = (__bf16)v;
    }
    if (idx < 160 * 512) {
      int n = idx >> 9, k = idx & 511;
      WamT[idx] = (__bf16)Wam[k * 160 + n];
    }
  } else {
    int t = (bx - 384) * 256 + threadIdx.x;  // [0, 32768)
    int n = t >> 5, c = t & 31;
    if (n < NPOS && c < 20) {
      float acc = 0.f;
#pragma unroll 8
      for (int pd = 0; pd < 192; ++pd) acc += pos_emb[n * 192 + pd] * Wpos[pd * 20 + c];
      int h = c >> 2, d = c & 3;
      peF[((size_t)h * NPOS + n) * 4 + d] = acc;
    }
  }
}

// ---------- projection GEMMs: (32768 x 512) @ (512 x NT*16), lm and am merged ----------
// Swapped MFMA operands: D[row = out-col n, col = A-row m] -> each thread owns 4
// consecutive output columns of one row -> vector epilogue stores.
template <int NT, bool IS_LM>
__device__ __forceinline__ void proj_body(const float* __restrict__ A, const __bf16* __restrict__ WT,
                                          const float* __restrict__ bias, __bf16* __restrict__ qk_out,
                                          float* __restrict__ p_out, int blk,
                                          __bf16 (*a_lds)[32], __bf16 (*w_lds)[32]) {
  const int tid = threadIdx.x;
  const int m0 = blk * 64;
  const int lane = tid & 63, w = tid >> 6;
  const int quad = lane >> 4, nl = lane & 15;

  floatx4 acc[NT];
#pragma unroll
  for (int j = 0; j < NT; ++j) acc[j] = floatx4{0.f, 0.f, 0.f, 0.f};

  const int arow = tid >> 2, aseg = tid & 3;
  for (int k0 = 0; k0 < 512; k0 += 32) {
    const float* ap = A + (size_t)(m0 + arow) * 512 + k0 + aseg * 8;
    float4 av0 = *(const float4*)ap;
    float4 av1 = *(const float4*)(ap + 4);
    bf16x8 pk;
    pk[0] = (__bf16)av0.x; pk[1] = (__bf16)av0.y; pk[2] = (__bf16)av0.z; pk[3] = (__bf16)av0.w;
    pk[4] = (__bf16)av1.x; pk[5] = (__bf16)av1.y; pk[6] = (__bf16)av1.z; pk[7] = (__bf16)av1.w;
    *(bf16x8*)&a_lds[arow][aseg * 8] = pk;
#pragma unroll
    for (int task = tid; task < NT * 64; task += 256) {
      int n = task >> 2, seg = task & 3;
      *(bf16x8*)&w_lds[n][seg * 8] = *(const bf16x8*)(WT + (size_t)n * 512 + k0 + seg * 8);
    }
    __syncthreads();
    bf16x8 afr = *(const bf16x8*)&a_lds[16 * w + nl][quad * 8];
#pragma unroll
    for (int jt = 0; jt < NT; ++jt) {
      bf16x8 bfr = *(const bf16x8*)&w_lds[jt * 16 + nl][quad * 8];
      // swapped: A = W fragment (rows = out cols n), B = activation fragment (cols = rows m)
      acc[jt] = __builtin_amdgcn_mfma_f32_16x16x32_bf16(bfr, afr, acc[jt], 0, 0, 0);
    }
    __syncthreads();
  }
  // D row = quad*4 + r = out col within tile; D col = nl = row m within wave tile
  const int m = m0 + 16 * w + nl;
#pragma unroll
  for (int jt = 0; jt < NT; ++jt) {
    const int c0 = jt * 16 + quad * 4;
    if (!IS_LM || c0 < 160) {
      float4 bv = *(const float4*)(bias + c0);
      bf16x4 o;
      o[0] = (__bf16)(acc[jt][0] + bv.x);
      o[1] = (__bf16)(acc[jt][1] + bv.y);
      o[2] = (__bf16)(acc[jt][2] + bv.z);
      o[3] = (__bf16)(acc[jt][3] + bv.w);
      *(bf16x4*)(qk_out + (size_t)m * 160 + c0) = o;
    } else if (c0 < 180) {
      float4 bv = *(const float4*)(bias + c0);
      float4 o;
      o.x = acc[jt][0] + bv.x; o.y = acc[jt][1] + bv.y;
      o.z = acc[jt][2] + bv.z; o.w = acc[jt][3] + bv.w;
      *(float4*)(p_out + (size_t)m * 20 + (c0 - 160)) = o;
    }
    // IS_LM && c0 >= 180: padding columns, discard
  }
}

__global__ __launch_bounds__(256, 4) void proj_kernel(
    const float* __restrict__ lm, const __bf16* __restrict__ WlmT, const float* __restrict__ blm,
    __bf16* __restrict__ qbuf, float* __restrict__ pbuf,
    const float* __restrict__ am, const __bf16* __restrict__ WamT, const float* __restrict__ bam,
    __bf16* __restrict__ kbuf) {
  __shared__ __align__(16) __bf16 a_lds[64][32];
  __shared__ __align__(16) __bf16 w_lds[192][32];
  if (blockIdx.x < 512)
    proj_body<12, true>(lm, WlmT, blm, qbuf, pbuf, blockIdx.x, a_lds, w_lds);
  else
    proj_body<10, false>(am, WamT, bam, kbuf, nullptr, blockIdx.x - 512, a_lds, w_lds);
}

// ---------- fused scores + rel-shift + mask + softmax ----------
// grid (8, 64, 5); block 256 = 4 waves; each wave: 16 q-rows x 512 s, s-major per thread:
// thread (w,quad,nl) owns row t = 16w+nl, cols s = jt*16 + quad*4 + [0,4).
__global__ __launch_bounds__(256, 2) void attn_kernel(
    const __bf16* __restrict__ q, const __bf16* __restrict__ k,
    const float* __restrict__ p, const float* __restrict__ peF,
    const unsigned char* __restrict__ mask, float* __restrict__ out) {
  __shared__ __align__(16) __bf16 k_lds[512][32];
  __shared__ __align__(16) __bf16 q_lds[64][32];
  __shared__ __align__(16) float p_lds[64][4];
  __shared__ __align__(16) float pe_lds[576 * 4];  // f32x4 per window index
  __shared__ float mask_lds[512];

  const int tid = threadIdx.x;
  const int t0 = blockIdx.x * 64;
  const int b = blockIdx.y;
  const int h = blockIdx.z;
  const int lane = tid & 63, w = tid >> 6;
  const int quad = lane >> 4, nl = lane & 15;

#pragma unroll
  for (int it = 0; it < 8; ++it) {
    int idx = tid + it * 256;
    int s = idx >> 2, c = idx & 3;
    *(bf16x8*)&k_lds[s][c * 8] =
        *(const bf16x8*)(k + (size_t)(s * BB + b) * 160 + h * 32 + c * 8);
  }
  {
    int s = tid >> 2, c = tid & 3;
    *(bf16x8*)&q_lds[s][c * 8] =
        *(const bf16x8*)(q + (size_t)((t0 + s) * BB + b) * 160 + h * 32 + c * 8);
  }
  if (tid < 64)
    *(float4*)&p_lds[tid][0] = *(const float4*)(p + (size_t)((t0 + tid) * BB + b) * 20 + h * 4);
  {
    int u0 = 448 - t0;  // window start in global u; i in [0,575)
    for (int i = tid; i < 575; i += 256)
      *(float4*)&pe_lds[i * 4] = *(const float4*)(peF + ((size_t)h * NPOS + u0 + i) * 4);
  }
  for (int i = tid; i < 512; i += 256)
    mask_lds[i] = mask[b * 512 + i] ? -1000.f : 0.f;
  __syncthreads();

  // content scores via MFMA (swapped operands), mask folded into C-init per s-row
  floatx4 acc[32];
  bf16x8 bq = *(const bf16x8*)&q_lds[16 * w + nl][quad * 8];
#pragma unroll
  for (int jt = 0; jt < 32; ++jt) {
    floatx4 cin = *(const floatx4*)&mask_lds[jt * 16 + quad * 4];
    bf16x8 ak = *(const bf16x8*)&k_lds[jt * 16 + nl][quad * 8];
    acc[jt] = __builtin_amdgcn_mfma_f32_16x16x32_bf16(ak, bq, cin, 0, 0, 0);
  }

  // pos scores: p[t] is per-thread constant; pe read as aligned float4 with imm offsets
  const int tl = 16 * w + nl;
  const floatx4 pv = *(const floatx4*)&p_lds[tl][0];
  const int ibase = quad * 4 - tl + 63;  // >= 0
  const floatx4* pef = (const floatx4*)pe_lds;
  float mx[4] = {-3.4e38f, -3.4e38f, -3.4e38f, -3.4e38f};
#pragma unroll
  for (int jt = 0; jt < 32; ++jt) {
    const int i0 = ibase + jt * 16;
    floatx4 v = acc[jt];
#pragma unroll
    for (int r = 0; r < 4; ++r) {
      floatx4 pe4 = pef[i0 + r];
      float val = v[r];
      val = fmaf(pv[0], pe4[0], val);
      val = fmaf(pv[1], pe4[1], val);
      val = fmaf(pv[2], pe4[2], val);
      val = fmaf(pv[3], pe4[3], val);
      v[r] = val;
      mx[r] = fmaxf(mx[r], val);
    }
    acc[jt] = v;
  }

  // row max: in-thread + across quads (lanes nl, nl+16, nl+32, nl+48 share a row)
  float mxa = fmaxf(fmaxf(mx[0], mx[1]), fmaxf(mx[2], mx[3]));
  mxa = fmaxf(mxa, __shfl_xor(mxa, 16, 64));
  mxa = fmaxf(mxa, __shfl_xor(mxa, 32, 64));

  float s0 = 0.f, s1 = 0.f, s2 = 0.f, s3 = 0.f;
#pragma unroll
  for (int jt = 0; jt < 32; ++jt) {
    floatx4 v = acc[jt];
    float e0 = __expf(v[0] - mxa);
    float e1 = __expf(v[1] - mxa);
    float e2 = __expf(v[2] - mxa);
    float e3 = __expf(v[3] - mxa);
    acc[jt] = floatx4{e0, e1, e2, e3};
    s0 += e0; s1 += e1; s2 += e2; s3 += e3;
  }
  float sum = (s0 + s1) + (s2 + s3);
  sum += __shfl_xor(sum, 16, 64);
  sum += __shfl_xor(sum, 32, 64);
  const float rinv = 1.0f / sum;

  float* op = out + (((size_t)h * BB + b) * TT + (t0 + tl)) * TT + quad * 4;
#pragma unroll
  for (int jt = 0; jt < 32; ++jt) {
    floatx4 v = acc[jt];
    v[0] *= rinv; v[1] *= rinv; v[2] *= rinv; v[3] *= rinv;
    *(floatx4*)(op + jt * 16) = v;
  }
}

extern "C" void kernel_launch(void* const* d_in, const int* in_sizes, int n_in,
                              void* d_out, int out_size, void* d_ws, size_t ws_size,
                              hipStream_t stream) {
  const float* lm = (const float*)d_in[0];
  const float* am = (const float*)d_in[1];
  const float* pos_emb = (const float*)d_in[2];
  const unsigned char* mask = (const unsigned char*)d_in[3];
  const float* Wlm = (const float*)d_in[4];
  const float* blm = (const float*)d_in[5];
  const float* Wam = (const float*)d_in[6];
  const float* bam = (const float*)d_in[7];
  const float* Wpos = (const float*)d_in[8];
  float* out = (float*)d_out;

  char* ws = (char*)d_ws;
  __bf16* qbuf = (__bf16*)ws;                          // 32768*160 bf16
  __bf16* kbuf = qbuf + (size_t)32768 * 160;           // 32768*160 bf16
  float* pbuf = (float*)(kbuf + (size_t)32768 * 160);  // 32768*20 f32
  float* peF = pbuf + (size_t)32768 * 20;              // 5*1024*4 f32 (padded alloc)
  __bf16* WlmT = (__bf16*)(peF + (size_t)5 * 1024 * 4);  // 192*512
  __bf16* WamT = WlmT + (size_t)192 * 512;               // 160*512

  prep_kernel<<<512, 256, 0, stream>>>(Wlm, Wam, pos_emb, Wpos, WlmT, WamT, peF);
  proj_kernel<<<1024, 256, 0, stream>>>(lm, WlmT, blm, qbuf, pbuf, am, WamT, bam, kbuf);
  attn_kernel<<<dim3(8, BB, HH), 256, 0, stream>>>(qbuf, kbuf, pbuf, peF, mask, out);
}